// Round 1
// baseline (329.495 us; speedup 1.0000x reference)
//
#include <hip/hip_runtime.h>
#include <stdint.h>

#define NB 4096   // query rows
#define NM 8192   // memory rows
#define ND 1024   // feature dim

typedef __attribute__((ext_vector_type(8))) short bf16x8;
typedef __attribute__((ext_vector_type(4))) float f32x4;
typedef __attribute__((ext_vector_type(8))) unsigned short u16x8;

static __device__ __forceinline__ unsigned short f2bf(float f) {
  union { float f; uint32_t u; } v; v.f = f;
  uint32_t u = v.u;
  u += 0x7fffu + ((u >> 16) & 1u);   // RNE
  return (unsigned short)(u >> 16);
}

static __device__ __forceinline__ void gload_lds16(const void* g, void* l) {
  __builtin_amdgcn_global_load_lds(
      (__attribute__((address_space(1))) void*)g,
      (__attribute__((address_space(3))) void*)l, 16, 0, 0);
}

// ---- L2-normalize rows of x [rows x 1024] fp32 -> bf16 out -----------------
__global__ void nrm_kernel(const float* __restrict__ x, unsigned short* __restrict__ out) {
  const int row = blockIdx.x, t = threadIdx.x;   // 256 threads, 4 floats each
  const float4 v = ((const float4*)(x + (size_t)row * ND))[t];
  float ss = v.x * v.x + v.y * v.y + v.z * v.z + v.w * v.w;
  #pragma unroll
  for (int o = 32; o > 0; o >>= 1) ss += __shfl_xor(ss, o);
  __shared__ float red[4];
  if ((t & 63) == 0) red[t >> 6] = ss;
  __syncthreads();
  ss = (red[0] + red[1]) + (red[2] + red[3]);
  const float sc = 1.0f / fmaxf(sqrtf(ss), 1e-12f);
  ushort4 o4;
  o4.x = f2bf(v.x * sc); o4.y = f2bf(v.y * sc);
  o4.z = f2bf(v.z * sc); o4.w = f2bf(v.w * sc);
  ((ushort4*)(out + (size_t)row * ND))[t] = o4;
}

// ---- transpose memn [8192x1024] bf16 -> memt [1024x8192] bf16 --------------
__global__ void tr_kernel(const unsigned short* __restrict__ memn, unsigned short* __restrict__ memt) {
  __shared__ unsigned short Ts[64][66];
  const int t = threadIdx.x;
  const int d0 = blockIdx.x * 64, m0 = blockIdx.y * 64;
  #pragma unroll
  for (int r = 0; r < 2; ++r) {
    const int lrow = r * 32 + (t >> 3);
    const int lcol = (t & 7) * 8;
    u16x8 v = *(const u16x8*)(memn + (size_t)(m0 + lrow) * ND + d0 + lcol);
    #pragma unroll
    for (int j = 0; j < 8; ++j) Ts[lcol + j][lrow] = v[j];
  }
  __syncthreads();
  #pragma unroll
  for (int r = 0; r < 2; ++r) {
    const int orow = r * 32 + (t >> 3);
    const int ocol = (t & 7) * 8;
    u16x8 o;
    #pragma unroll
    for (int j = 0; j < 8; ++j) o[j] = Ts[orow][ocol + j];
    *(u16x8*)(memt + (size_t)(d0 + orow) * NM + m0 + ocol) = o;
  }
}

// ---- row softmax in-place on sim [4096x8192] fp32; optional bf16 copy ------
__global__ void softmax_kernel(float* __restrict__ sim, unsigned short* __restrict__ attnb, int wb) {
  const int row = blockIdx.x, t = threadIdx.x;
  float* prow = sim + (size_t)row * NM;
  float4 v[8];
  #pragma unroll
  for (int i = 0; i < 8; ++i) v[i] = ((const float4*)prow)[i * 256 + t];
  float mx = -3.4e38f;
  #pragma unroll
  for (int i = 0; i < 8; ++i)
    mx = fmaxf(mx, fmaxf(fmaxf(v[i].x, v[i].y), fmaxf(v[i].z, v[i].w)));
  #pragma unroll
  for (int o = 32; o > 0; o >>= 1) mx = fmaxf(mx, __shfl_xor(mx, o));
  __shared__ float red[8];
  if ((t & 63) == 0) red[t >> 6] = mx;
  __syncthreads();
  mx = fmaxf(fmaxf(red[0], red[1]), fmaxf(red[2], red[3]));
  float s = 0.f;
  #pragma unroll
  for (int i = 0; i < 8; ++i) {
    v[i].x = __expf(v[i].x - mx); v[i].y = __expf(v[i].y - mx);
    v[i].z = __expf(v[i].z - mx); v[i].w = __expf(v[i].w - mx);
    s += (v[i].x + v[i].y) + (v[i].z + v[i].w);
  }
  #pragma unroll
  for (int o = 32; o > 0; o >>= 1) s += __shfl_xor(s, o);
  if ((t & 63) == 0) red[4 + (t >> 6)] = s;
  __syncthreads();
  s = (red[4] + red[5]) + (red[6] + red[7]);
  const float inv = 1.0f / s;
  #pragma unroll
  for (int i = 0; i < 8; ++i) {
    v[i].x *= inv; v[i].y *= inv; v[i].z *= inv; v[i].w *= inv;
    ((float4*)prow)[i * 256 + t] = v[i];
    if (wb) {
      ushort4 b;
      b.x = f2bf(v[i].x); b.y = f2bf(v[i].y); b.z = f2bf(v[i].z); b.w = f2bf(v[i].w);
      *(ushort4*)(attnb + (size_t)row * NM + (size_t)(i * 256 + t) * 4) = b;
    }
  }
}

// ---- GEMM: C[M,N] = A[M,K] * Bt[N,K]^T, bf16 MFMA, fp32 out ---------------
// 128x128 tile, BK=64, 256 threads (4 waves in 2x2), 16x16x32 bf16 MFMA.
template<bool A_BF16>
__global__ __launch_bounds__(256) void gemm_kernel(
    const void* __restrict__ Ap, const unsigned short* __restrict__ Bt,
    float* __restrict__ C, int Kdim, int Ndim)
{
  __shared__ __align__(16) unsigned short As[128 * 64];
  __shared__ __align__(16) unsigned short Bs[128 * 64];
  const int t = threadIdx.x;
  const int wv = t >> 6, l = t & 63;
  const int wr = wv >> 1, wc = wv & 1;
  const int brow = blockIdx.x, bcol = blockIdx.y;
  const int srow = t >> 3;            // 0..31 row within a 32-row stage group
  const int scol = (t & 7) * 8;       // element col offset within 64-wide tile
  const int lr15 = l & 15, lhi = l >> 4;

  f32x4 acc[4][4] = {};

  for (int kt = 0; kt < Kdim; kt += 64) {
    if constexpr (A_BF16) {
      const unsigned short* A = (const unsigned short*)Ap;
      #pragma unroll
      for (int r = 0; r < 4; ++r)
        gload_lds16(A + (size_t)(brow * 128 + r * 32 + srow) * Kdim + kt + scol,
                    (char*)As + r * 4096 + wv * 1024);
    } else {
      const float* A = (const float*)Ap;    // fp32 attn -> cvt to bf16 in regs
      #pragma unroll
      for (int r = 0; r < 8; ++r) {
        const int idx4 = r * 256 + t;
        const int row = idx4 >> 4, c4 = (idx4 & 15) * 4;
        float4 fv = *(const float4*)(A + (size_t)(brow * 128 + row) * Kdim + kt + c4);
        ushort4 b;
        b.x = f2bf(fv.x); b.y = f2bf(fv.y); b.z = f2bf(fv.z); b.w = f2bf(fv.w);
        *(ushort4*)(As + row * 64 + c4) = b;
      }
    }
    #pragma unroll
    for (int r = 0; r < 4; ++r)
      gload_lds16(Bt + (size_t)(bcol * 128 + r * 32 + srow) * Kdim + kt + scol,
                  (char*)Bs + r * 4096 + wv * 1024);
    __syncthreads();
    #pragma unroll
    for (int kk = 0; kk < 2; ++kk) {
      bf16x8 a[4], b[4];
      #pragma unroll
      for (int m = 0; m < 4; ++m)
        a[m] = *(const bf16x8*)(As + (wr * 64 + m * 16 + lr15) * 64 + kk * 32 + lhi * 8);
      #pragma unroll
      for (int n = 0; n < 4; ++n)
        b[n] = *(const bf16x8*)(Bs + (wc * 64 + n * 16 + lr15) * 64 + kk * 32 + lhi * 8);
      #pragma unroll
      for (int m = 0; m < 4; ++m)
        #pragma unroll
        for (int n = 0; n < 4; ++n)
          acc[m][n] = __builtin_amdgcn_mfma_f32_16x16x32_bf16(a[m], b[n], acc[m][n], 0, 0, 0);
    }
    __syncthreads();
  }
  // C/D layout: col = lane&15, row = (lane>>4)*4 + reg  [learn_hip m89/m91]
  const int crow0 = brow * 128 + wr * 64 + lhi * 4;
  const int ccol0 = bcol * 128 + wc * 64 + lr15;
  #pragma unroll
  for (int m = 0; m < 4; ++m)
    #pragma unroll
    for (int n = 0; n < 4; ++n)
      #pragma unroll
      for (int j = 0; j < 4; ++j)
        C[(size_t)(crow0 + m * 16 + j) * Ndim + ccol0 + n * 16] = acc[m][n][j];
}

extern "C" void kernel_launch(void* const* d_in, const int* in_sizes, int n_in,
                              void* d_out, int out_size, void* d_ws, size_t ws_size,
                              hipStream_t stream) {
  const float* q   = (const float*)d_in[0];
  const float* mem = (const float*)d_in[1];
  float* mf   = (float*)d_out;                       // [4096 x 1024]
  float* attn = (float*)d_out + (size_t)NB * ND;     // [4096 x 8192]
  char* ws = (char*)d_ws;
  unsigned short* qn    = (unsigned short*)(ws);                      // 8 MiB
  unsigned short* memn  = (unsigned short*)(ws + ((size_t)8  << 20)); // 16 MiB
  unsigned short* memt  = (unsigned short*)(ws + ((size_t)24 << 20)); // 16 MiB
  unsigned short* attnb = (unsigned short*)(ws + ((size_t)40 << 20)); // 64 MiB
  const bool useb = ws_size >= ((size_t)104 << 20);

  hipLaunchKernelGGL(nrm_kernel, dim3(NM), dim3(256), 0, stream, mem, memn);
  hipLaunchKernelGGL(nrm_kernel, dim3(NB), dim3(256), 0, stream, q, qn);
  hipLaunchKernelGGL(tr_kernel, dim3(ND / 64, NM / 64), dim3(256), 0, stream, memn, memt);
  // sim = qn * memn^T  -> fp32 into attn region (pre-softmax scratch)
  hipLaunchKernelGGL((gemm_kernel<true>), dim3(NB / 128, NM / 128), dim3(256), 0, stream,
                     (const void*)qn, memn, attn, ND, NM);
  hipLaunchKernelGGL(softmax_kernel, dim3(NB), dim3(256), 0, stream, attn, attnb, useb ? 1 : 0);
  // mf = attn * memn  (A = bf16 attnb if ws allows, else fp32 attn with cvt)
  if (useb)
    hipLaunchKernelGGL((gemm_kernel<true>), dim3(NB / 128, ND / 128), dim3(256), 0, stream,
                       (const void*)attnb, memt, mf, NM, ND);
  else
    hipLaunchKernelGGL((gemm_kernel<false>), dim3(NB / 128, ND / 128), dim3(256), 0, stream,
                       (const void*)attn, memt, mf, NM, ND);
}